// Round 4
// baseline (834.289 us; speedup 1.0000x reference)
//
#include <hip/hip_runtime.h>

// 16-qubit, depth-4, batch-512 statevector simulator — 7-sweep, packed-FP32,
// full-batch (L3-blocking refuted in round 3), exact-32KB LDS for 5 blocks/CU.
//
// State: 512 x 65536 complex64 = 256 MiB in d_ws.
// Reference qubit q <-> flat-index bit beta = 15-q.
// Memory layout per batch: amp with basis index g stored at m = (g>>3) | ((g&7)<<13).
//
// Partition A (blocks fix g bits 0..2): local j = m bits 0..12, j_b = g_{b+3},
//   j bit b <-> qubit 12-b.
// Partition B (blocks fix g bits 12..14): local d: d0..8 = g3..11, d9 = g15,
//   d10..12 = g0..2; d bit b<=8 <-> qubit 12-b; d9<->q0; d10,11,12 <-> q15,14,13.
//
// Chain perm F (16 CNOTs): source s = F(dest f): s_b = f_b^f_{b+1} (b=0..13),
//   s14 = f14^f15^f0, s15 = f15^f0.  Split: main (g3..15, done in A) then tail
//   (done in B as register rename permB).  Schedule (7 sweeps):
//     1. qc_gen:        analytic (x)(U_{L0,q} RX(x_q))|0>, main0 folded. Write-only.
//     2. qc_B_heavy(1): tail0 (reg rename) + L1 gates on 13 B-local qubits.
//     3. qc_A_lite(1):  L1 gates q3,q2,q1 + main1 (LDS-staged writeback).
//     4. qc_B_heavy(2): tail1 + L2 x13.
//     5. qc_A_lite(2):  L2 q3,q2,q1 + main2.
//     6. qc_B_heavy(3): tail2 + L3 x13.
//     7. qc_A_final:    L3 q3,q2,q1 + expZ with main3.tail3 folded as relabel.
//
// This revision: LDS per block = EXACTLY 32768 B (was 33280) so occupancy goes
// 4 -> 5 blocks/CU (16 -> 20 waves).  The U-matrix table lives INSIDE the
// transpose buffer S (S is dead during gate phases); threads t<13 keep their
// own U in registers and re-write S[0..51] before each gate phase.  Gate reads
// are wave-uniform -> LDS broadcast, conflict-free.  __launch_bounds__(256,5)
// caps VGPR at 102 (measured ~64 needed).

#define NQ 16
#define TPB 256

typedef float __attribute__((ext_vector_type(2))) f2;   // (re, im)

__device__ __forceinline__ f2 f2s(float s) { return (f2){s, s}; }

// a (*) b  (complex mul, packed: pk_mul + pk_fma)
__device__ __forceinline__ f2 cmulpk(f2 a, f2 b) {
    f2 bs = { -b.y, b.x };
    f2 r = f2s(a.x) * b;
    return __builtin_elementwise_fma(f2s(a.y), bs, r);
}

// U = RY(t2) * RX(t1) * RZ(t0), row-major [u00,u01,u10,u11]
__device__ __forceinline__ void computeU(const float* params, int layer, int q, f2* U) {
    const float* p = params + (layer*NQ + q)*3;
    float s0, c0, s1, c1, s2, c2;
    sincosf(0.5f*p[0], &s0, &c0);
    sincosf(0.5f*p[1], &s1, &c1);
    sincosf(0.5f*p[2], &s2, &c2);
    f2 m00 = { c1*c0, -c1*s0};
    f2 m01 = { s1*s0, -s1*c0};
    f2 m10 = {-s1*s0, -s1*c0};
    f2 m11 = { c1*c0,  c1*s0};
    U[0] = c2*m00 - s2*m10;
    U[1] = c2*m01 - s2*m11;
    U[2] = s2*m00 + c2*m10;
    U[3] = s2*m01 + c2*m11;
}

// 1q gate on register array A[32], pairing a <-> a|MASK.  8 packed ops/pair.
template<int MASK>
__device__ __forceinline__ void gate32(f2* A, f2 u00, f2 u01, f2 u10, f2 u11) {
    #pragma unroll
    for (int a = 0; a < 32; ++a) {
        if (!(a & MASK)) {
            f2 x = A[a], y = A[a | MASK];
            f2 xs = { -x.y, x.x };
            f2 ys = { -y.y, y.x };
            f2 nx = f2s(u00.x) * x;
            nx = __builtin_elementwise_fma(f2s(u00.y), xs, nx);
            nx = __builtin_elementwise_fma(f2s(u01.x), y,  nx);
            nx = __builtin_elementwise_fma(f2s(u01.y), ys, nx);
            f2 ny = f2s(u10.x) * x;
            ny = __builtin_elementwise_fma(f2s(u10.y), xs, ny);
            ny = __builtin_elementwise_fma(f2s(u11.x), y,  ny);
            ny = __builtin_elementwise_fma(f2s(u11.y), ys, ny);
            A[a] = nx; A[a | MASK] = ny;
        }
    }
}

// tail perm on B's register coords (bits = d0, d9, d10, d11, d12)
__device__ __forceinline__ constexpr int permB(int ad) {
    return (ad & 1)
         | ((((ad >> 1) ^ (ad >> 2)) & 1) << 1)
         | ((((ad >> 2) ^ (ad >> 3)) & 1) << 2)
         | ((((ad >> 3) ^ (ad >> 4)) & 1) << 3)
         | ((((ad >> 4) ^  ad      ) & 1) << 4);
}

// Sweep 1: analytic product state, main0 folded into source-index evaluation.
__global__ __launch_bounds__(TPB) void qc_gen(
    const float* __restrict__ x, const float* __restrict__ params,
    f2* __restrict__ st)
{
    __shared__ f2 V[16][2];
    const int t    = threadIdx.x;
    const int b    = blockIdx.x >> 3;
    const int fix3 = blockIdx.x & 7;
    f2* base = st + ((size_t)b << NQ) + (fix3 << 13);

    if (t < 16) {                   // qubit t, g bit 15-t
        f2 U[4];
        computeU(params, 0, t, U);
        float s, c;
        sincosf(0.5f * x[b*NQ + t], &s, &c);
        // w = U * (cos h, -i sin h)^T
        V[15 - t][0] = (f2){U[0].x*c + U[1].y*s, U[0].y*c - U[1].x*s};
        V[15 - t][1] = (f2){U[2].x*c + U[3].y*s, U[2].y*c - U[3].x*s};
    }
    __syncthreads();

    // dest D = 2(t+256k)+o | h<<12 ; source i = D ^ ((D>>1)&0xFFF):
    // i0=o^t0; i_b = t_{b-1}^t_b (b=1..7); i8=t7^k0; i9=k0^k1; i10=k1^k2;
    // i11=k2^h; i12=h.  g = fix3 | (i<<3).
    f2 cf = cmulpk(V[0][fix3 & 1], V[1][(fix3 >> 1) & 1]);
    cf = cmulpk(cf, V[2][(fix3 >> 2) & 1]);
    #pragma unroll
    for (int bb = 1; bb <= 7; ++bb)
        cf = cmulpk(cf, V[3 + bb][((t >> (bb - 1)) ^ (t >> bb)) & 1]);

    const int t0 = t & 1, t7 = (t >> 7) & 1;
    float4* dst = (float4*)base;
    #pragma unroll
    for (int h = 0; h < 2; ++h) {
        #pragma unroll
        for (int k = 0; k < 8; ++k) {
            const int k0 = k & 1, k1 = (k >> 1) & 1, k2 = (k >> 2) & 1;
            f2 pk = cmulpk(cf, V[11][t7 ^ k0]);
            pk = cmulpk(pk, V[12][k0 ^ k1]);
            pk = cmulpk(pk, V[13][k1 ^ k2]);
            pk = cmulpk(pk, V[14][k2 ^ h]);
            pk = cmulpk(pk, V[15][h]);
            f2 w0 = cmulpk(pk, V[3][t0]);        // o=0
            f2 w1 = cmulpk(pk, V[3][1 ^ t0]);    // o=1
            dst[(t + 256*k) | (h << 11)] = make_float4(w0.x, w0.y, w1.x, w1.y);
        }
    }
}

// Sweeps 2,4,6: tail(lm-1) rename + layer-lm gates on all 13 B-local qubits.
// LDS = exactly 32 KB: U-table lives in S[0..51], re-written before each gate
// phase from per-thread Ureg (t<13).  5 blocks/CU.
__global__ __launch_bounds__(TPB, 5) void qc_B_heavy(
    const float* __restrict__ params, f2* __restrict__ st, int lm)
{
    __shared__ __align__(16) f2 S[4096];       // 32768 B exactly

    const int t    = threadIdx.x;
    const int b    = blockIdx.x >> 3;
    const int fixb = blockIdx.x & 7;            // g bits 12..14
    f2* base = st + ((size_t)b << NQ);

    // U slots (idx i at S[4i..4i+3]): 0:q12(d0) 1:q0(d9) 2:q15(d10) 3:q14(d11)
    //   4:q13(d12)  5..8: q11..q8 (d1..4)  9..12: q7..q4 (d5..8)
    f2 Ureg[4];
    if (t < 13) {
        int qb = (t == 0) ? 12 : (t == 1) ? 0 : (t < 5) ? (17 - t) : (16 - t);
        computeU(params, lm, qb, Ureg);
        #pragma unroll
        for (int i = 0; i < 4; ++i) S[4*t + i] = Ureg[i];
    }

    // load arr1-d: reg a: bit0 = d0, bits1..4 = d9..12; thread bits = d1..8
    f2 R[32];
    #pragma unroll
    for (int k = 0; k < 16; ++k) {
        int j = 2*(t + 256*k);
        int m = (j & 511) | (fixb << 9) | (((j >> 9) & 1) << 12) | ((j >> 10) << 13);
        float4 v = *(const float4*)(base + m);
        R[2*k]   = (f2){v.x, v.y};
        R[2*k+1] = (f2){v.z, v.w};
    }
    // tail perm of layer lm-1: pure compile-time register rename
    f2 A[32];
    #pragma unroll
    for (int a = 0; a < 32; ++a) A[a] = R[permB(a)];
    __syncthreads();                             // U-table ready

    // arr1 gates (layer lm): d0->q12, d9->q0, d10..12 -> q15,q14,q13
    gate32<1> (A, S[0],  S[1],  S[2],  S[3]);
    gate32<2> (A, S[4],  S[5],  S[6],  S[7]);
    gate32<4> (A, S[8],  S[9],  S[10], S[11]);
    gate32<8> (A, S[12], S[13], S[14], S[15]);
    gate32<16>(A, S[16], S[17], S[18], S[19]);

    // Transpose 1: arr1 {0,9,10,11,12} -> arr2 {1,2,3,4,12}
    #pragma unroll
    for (int h = 0; h < 2; ++h) {
        __syncthreads();                         // orders U reads / prev reads vs writes
        #pragma unroll
        for (int c = 0; c < 8; ++c) {
            int slot = ((t << 1) | (c << 9)) ^ (((t >> 4) & 7) << 1);
            f2 a0 = A[h*16 + 2*c], a1 = A[h*16 + 2*c + 1];
            *(float4*)&S[slot] = make_float4(a0.x, a0.y, a1.x, a1.y);
        }
        __syncthreads();
        #pragma unroll
        for (int rr = 0; rr < 16; ++rr) {
            int jj = (t & 1) | (rr << 1) | (((t >> 1) & 15) << 5) | (((t >> 5) & 7) << 9);
            A[h*16 + rr] = S[jj ^ (((t >> 1) & 7) << 1)];
        }
    }

    // restore U-table (clobbered by T1), then arr2 gates: d1..4 -> q11,q10,q9,q8
    __syncthreads();                             // all T1 reads done
    if (t < 13) {
        #pragma unroll
        for (int i = 0; i < 4; ++i) S[4*t + i] = Ureg[i];
    }
    __syncthreads();
    gate32<1>(A, S[20], S[21], S[22], S[23]);
    gate32<2>(A, S[24], S[25], S[26], S[27]);
    gate32<4>(A, S[28], S[29], S[30], S[31]);
    gate32<8>(A, S[32], S[33], S[34], S[35]);

    // Transpose 2: arr2 -> arr3 {5,6,7,8,12}
    #pragma unroll
    for (int h = 0; h < 2; ++h) {
        __syncthreads();
        #pragma unroll
        for (int rr = 0; rr < 16; ++rr) {
            int jj = (t & 1) | (rr << 1) | (((t >> 1) & 15) << 5) | (((t >> 5) & 7) << 9);
            S[jj ^ (((t >> 1) & 7) << 1)] = A[h*16 + rr];
        }
        __syncthreads();
        #pragma unroll
        for (int rr = 0; rr < 16; ++rr) {
            int jj = (t & 31) | (rr << 5) | (((t >> 5) & 7) << 9);
            A[h*16 + rr] = S[jj ^ ((rr & 7) << 1)];
        }
    }

    // restore U-table (clobbered by T2), then arr3 gates: d5..8 -> q7,q6,q5,q4
    __syncthreads();
    if (t < 13) {
        #pragma unroll
        for (int i = 0; i < 4; ++i) S[4*t + i] = Ureg[i];
    }
    __syncthreads();
    gate32<1>(A, S[36], S[37], S[38], S[39]);
    gate32<2>(A, S[40], S[41], S[42], S[43]);
    gate32<4>(A, S[44], S[45], S[46], S[47]);
    gate32<8>(A, S[48], S[49], S[50], S[51]);

    // direct store from arr3 (no perm)
    #pragma unroll
    for (int h = 0; h < 2; ++h) {
        #pragma unroll
        for (int rr = 0; rr < 16; ++rr) {
            int d = (t & 31) | (rr << 5) | (((t >> 5) & 7) << 9) | (h << 12);
            int m = (d & 511) | (fixb << 9) | (((d >> 9) & 1) << 12) | ((d >> 10) << 13);
            base[m] = A[h*16 + rr];
        }
    }
}

// Sweeps 3,5: layer-l gates q3,q2,q1 (j9,j10,j11) + main(l) perm in writeback.
// LDS = exactly 32 KB: U-table in S[0..11], read JIT before staging clobbers it.
__global__ __launch_bounds__(TPB, 5) void qc_A_lite(
    const float* __restrict__ params, f2* __restrict__ st, int layer)
{
    __shared__ __align__(16) f2 S[4096];       // 32768 B exactly
    const int t    = threadIdx.x;
    const int b    = blockIdx.x >> 3;
    const int fix3 = blockIdx.x & 7;
    f2* base = st + ((size_t)b << NQ) + (fix3 << 13);

    if (t < 3) {                                 // U idx t: 0=q3 1=q2 2=q1
        f2 Ureg[4];
        computeU(params, layer, 3 - t, Ureg);
        #pragma unroll
        for (int i = 0; i < 4; ++i) S[4*t + i] = Ureg[i];
    }

    f2 A[32];
    const float4* src = (const float4*)base;
    #pragma unroll
    for (int k = 0; k < 16; ++k) {
        float4 v = src[t + 256*k];
        A[2*k]   = (f2){v.x, v.y};
        A[2*k+1] = (f2){v.z, v.w};
    }
    __syncthreads();                             // U-table ready

    gate32<2>(A, S[0], S[1], S[2],  S[3]);       // j9  q3
    gate32<4>(A, S[4], S[5], S[6],  S[7]);       // j10 q2
    gate32<8>(A, S[8], S[9], S[10], S[11]);      // j11 q1

    // writeback: stage at arr1 positions, read with main-chain perm, store coalesced
    float4* dst = (float4*)base;
    #pragma unroll
    for (int h = 0; h < 2; ++h) {
        __syncthreads();                         // orders U reads vs staging writes
        #pragma unroll
        for (int c = 0; c < 8; ++c) {            // arr1: j = o | (t<<1) | (c<<9), j12=h
            int slot = ((t << 1) | (c << 9)) ^ (((t >> 4) & 7) << 1);
            f2 a0 = A[h*16 + 2*c], a1 = A[h*16 + 2*c + 1];
            *(float4*)&S[slot] = make_float4(a0.x, a0.y, a1.x, a1.y);
        }
        __syncthreads();
        #pragma unroll
        for (int k = 0; k < 8; ++k) {            // dest d' = 2(t+256k), bit12 = h
            int d  = 2*(t + 256*k);
            int i0 = d ^ (d >> 1) ^ (h << 11);
            int i1 = (d+1) ^ ((d+1) >> 1) ^ (h << 11);
            f2 a0 = S[i0 ^ (((i0 >> 5) & 7) << 1)];
            f2 a1 = S[i1 ^ (((i1 >> 5) & 7) << 1)];
            dst[(t + 256*k) | (h << 11)] = make_float4(a0.x, a0.y, a1.x, a1.y);
        }
    }
}

// Sweep 7: L3 gates q3,q2,q1, then expZ with main3.tail3 folded as relabel.
// u bits: 0..2 = fix3, 3 = a0, 4..11 = t, 12..15 = a1..a4.
// f_b = parity(u>>b) (b<=14), f15 = parity(u & 0x7FFF).
__global__ __launch_bounds__(TPB) void qc_A_final(
    const float* __restrict__ params, const f2* __restrict__ st,
    float* __restrict__ out)
{
    __shared__ f2 Ush[3][4];
    const int t    = threadIdx.x;
    const int b    = blockIdx.x >> 3;
    const int fix3 = blockIdx.x & 7;
    const f2* base = st + ((size_t)b << NQ) + (fix3 << 13);

    if (t < 3) computeU(params, 3, 3 - t, Ush[t]);

    f2 A[32];
    const float4* src = (const float4*)base;
    #pragma unroll
    for (int k = 0; k < 16; ++k) {
        float4 v = src[t + 256*k];
        A[2*k]   = (f2){v.x, v.y};
        A[2*k+1] = (f2){v.z, v.w};
    }
    __syncthreads();

    gate32<2>(A, Ush[0][0], Ush[0][1], Ush[0][2], Ush[0][3]);   // j9  q3
    gate32<4>(A, Ush[1][0], Ush[1][1], Ush[1][2], Ush[1][3]);   // j10 q2
    gate32<8>(A, Ush[2][0], Ush[2][1], Ush[2][2], Ush[2][3]);   // j11 q1

    // 5 register-parity sign buckets:
    // M1 = par(a1..a4) -> q3..q11 ; M2 = par(a0..a4) -> q12..q15
    // M3 = par(a2..a4) -> q2 ; M4 = par(a3,a4) -> q1 ; M5 = par(a0..a3) -> q0
    float m1 = 0.f, m2 = 0.f, m3 = 0.f, m4 = 0.f, m5 = 0.f;
    #pragma unroll
    for (int a = 0; a < 32; ++a) {
        float p = A[a].x*A[a].x + A[a].y*A[a].y;
        m1 += (__popc(a & 0x1E) & 1) ? -p : p;
        m2 += (__popc(a & 0x1F) & 1) ? -p : p;
        m3 += (__popc(a & 0x1C) & 1) ? -p : p;
        m4 += (__popc(a & 0x18) & 1) ? -p : p;
        m5 += (__popc(a & 0x0F) & 1) ? -p : p;
    }
    const int pt = __popc(t) & 1;
    const int pf = __popc(fix3) & 1;
    float acc[NQ];
    acc[0] = ((pt ^ pf) & 1) ? -m5 : m5;         // f15
    acc[1] = m4;                                  // f14
    acc[2] = m3;                                  // f13
    acc[3] = m1;                                  // f12
    #pragma unroll
    for (int q = 4; q <= 11; ++q) {               // f_{15-q}: t-part = par(t >> (11-q))
        int s = __popc(t >> (11 - q)) & 1;
        acc[q] = s ? -m1 : m1;
    }
    acc[12] = pt ? -m2 : m2;
    acc[13] = ((pt ^ (fix3 >> 2)) & 1) ? -m2 : m2;
    acc[14] = ((pt ^ __popc(fix3 >> 1)) & 1) ? -m2 : m2;
    acc[15] = ((pt ^ pf) & 1) ? -m2 : m2;

    #pragma unroll
    for (int q = 0; q < NQ; ++q) {
        float v = acc[q];
        v += __shfl_down(v, 32, 64);
        v += __shfl_down(v, 16, 64);
        v += __shfl_down(v,  8, 64);
        v += __shfl_down(v,  4, 64);
        v += __shfl_down(v,  2, 64);
        v += __shfl_down(v,  1, 64);
        acc[q] = v;
    }
    if ((t & 63) == 0) {
        #pragma unroll
        for (int q = 0; q < NQ; ++q)
            atomicAdd(&out[b*NQ + q], acc[q]);
    }
}

extern "C" void kernel_launch(void* const* d_in, const int* in_sizes, int n_in,
                              void* d_out, int out_size, void* d_ws, size_t ws_size,
                              hipStream_t stream)
{
    (void)in_sizes; (void)n_in; (void)ws_size;
    const float* x      = (const float*)d_in[0];   // (512,16) fp32
    const float* params = (const float*)d_in[1];   // (4,16,3) fp32
    float* out = (float*)d_out;                    // (512,16) fp32
    f2* st = (f2*)d_ws;                            // 256 MiB state

    hipMemsetAsync(d_out, 0, (size_t)out_size * sizeof(float), stream);
    qc_gen    <<<dim3(512*8), dim3(TPB), 0, stream>>>(x, params, st);
    qc_B_heavy<<<dim3(512*8), dim3(TPB), 0, stream>>>(params, st, 1);
    qc_A_lite <<<dim3(512*8), dim3(TPB), 0, stream>>>(params, st, 1);
    qc_B_heavy<<<dim3(512*8), dim3(TPB), 0, stream>>>(params, st, 2);
    qc_A_lite <<<dim3(512*8), dim3(TPB), 0, stream>>>(params, st, 2);
    qc_B_heavy<<<dim3(512*8), dim3(TPB), 0, stream>>>(params, st, 3);
    qc_A_final<<<dim3(512*8), dim3(TPB), 0, stream>>>(params, st, out);
}

// Round 5
// 597.881 us; speedup vs baseline: 1.3954x; 1.3954x over previous
//
#include <hip/hip_runtime.h>

// 16-qubit, depth-4, batch-512 statevector simulator — 6-sweep, packed-FP32.
// Round-4 (5 blocks/CU) regressed: HBM write amplification + extra barriers.
// This version = round-2 structure (best: 635 us) + layer-1 B-sweep fused with
// analytic product-state generation (deletes the qc_gen sweep AND B(1)'s load).
//
// State: 512 x 65536 complex64 = 256 MiB in d_ws.
// Reference qubit q <-> flat-index bit beta = 15-q.
// Memory layout per batch: amp with basis index g stored at m = (g>>3) | ((g&7)<<13).
//
// Partition A (blocks fix g bits 0..2): local j = m bits 0..12, j_b = g_{b+3}.
// Partition B (blocks fix g bits 12..14): local d: d0..8 = g3..11, d9 = g15,
//   d10..12 = g0..2.
//
// Chain perm (16 CNOTs), inverse (source s from dest f):
//   s_b = f_b^f_{b+1} (b=0..13), s14 = f14^f15^f0, s15 = f15^f0.
// Factorization: s = main(tail(f)) — tail applied to the index first (B-local:
// g15^=g0, g0^=g1, g1^=g2, g2^=g3), then main (A-local: g_b^=g_{b+1}, b=3..14).
// Schedule (6 sweeps):
//   1. qc_B1_gen:   analytic (x)(U_{L0,q} RX(x_q))|0> at full-chain0-permuted
//                   indices (product tree, no loads) + L1 gates on 13 B-qubits.
//   2. qc_A_lite(1): L1 gates q3,q2,q1 + main1 (LDS-staged writeback).
//   3. qc_B_heavy(2): tail1 (reg rename) + L2 x13.
//   4. qc_A_lite(2): L2 q3,q2,q1 + main2.
//   5. qc_B_heavy(3): tail2 + L3 x13.
//   6. qc_A_final:  L3 q3,q2,q1 + expZ with main3.tail3 folded as relabel.

#define NQ 16
#define TPB 256

typedef float __attribute__((ext_vector_type(2))) f2;   // (re, im)

__device__ __forceinline__ f2 f2s(float s) { return (f2){s, s}; }

// a (*) b  (complex mul, packed: pk_mul + pk_fma)
__device__ __forceinline__ f2 cmulpk(f2 a, f2 b) {
    f2 bs = { -b.y, b.x };
    f2 r = f2s(a.x) * b;
    return __builtin_elementwise_fma(f2s(a.y), bs, r);
}

// U = RY(t2) * RX(t1) * RZ(t0), row-major [u00,u01,u10,u11]
__device__ __forceinline__ void computeU(const float* params, int layer, int q, f2* U) {
    const float* p = params + (layer*NQ + q)*3;
    float s0, c0, s1, c1, s2, c2;
    sincosf(0.5f*p[0], &s0, &c0);
    sincosf(0.5f*p[1], &s1, &c1);
    sincosf(0.5f*p[2], &s2, &c2);
    f2 m00 = { c1*c0, -c1*s0};
    f2 m01 = { s1*s0, -s1*c0};
    f2 m10 = {-s1*s0, -s1*c0};
    f2 m11 = { c1*c0,  c1*s0};
    U[0] = c2*m00 - s2*m10;
    U[1] = c2*m01 - s2*m11;
    U[2] = s2*m00 + c2*m10;
    U[3] = s2*m01 + c2*m11;
}

// 1q gate on register array A[32], pairing a <-> a|MASK.  8 packed ops/pair.
template<int MASK>
__device__ __forceinline__ void gate32(f2* A, f2 u00, f2 u01, f2 u10, f2 u11) {
    #pragma unroll
    for (int a = 0; a < 32; ++a) {
        if (!(a & MASK)) {
            f2 x = A[a], y = A[a | MASK];
            f2 xs = { -x.y, x.x };
            f2 ys = { -y.y, y.x };
            f2 nx = f2s(u00.x) * x;
            nx = __builtin_elementwise_fma(f2s(u00.y), xs, nx);
            nx = __builtin_elementwise_fma(f2s(u01.x), y,  nx);
            nx = __builtin_elementwise_fma(f2s(u01.y), ys, nx);
            f2 ny = f2s(u10.x) * x;
            ny = __builtin_elementwise_fma(f2s(u10.y), xs, ny);
            ny = __builtin_elementwise_fma(f2s(u11.x), y,  ny);
            ny = __builtin_elementwise_fma(f2s(u11.y), ys, ny);
            A[a] = nx; A[a | MASK] = ny;
        }
    }
}

// tail perm on B's register coords (bits = d0, d9, d10, d11, d12)
__device__ __forceinline__ constexpr int permB(int ad) {
    return (ad & 1)
         | ((((ad >> 1) ^ (ad >> 2)) & 1) << 1)
         | ((((ad >> 2) ^ (ad >> 3)) & 1) << 2)
         | ((((ad >> 3) ^ (ad >> 4)) & 1) << 3)
         | ((((ad >> 4) ^  ad      ) & 1) << 4);
}

// Common B-sweep body: 13 gates (arr1/arr2/arr3 arrangements, 2 LDS transposes)
// + direct store.  A[] on entry holds arr1-arrangement amplitudes, Ush ready.
__device__ __forceinline__ void b_gates_and_store(
    f2* A, f2* S, const f2 (*Ush)[4], int t, int fixb, f2* base)
{
    // arr1 gates: d0->q12, d9->q0, d10..12 -> q15,q14,q13
    gate32<1> (A, Ush[0][0],  Ush[0][1],  Ush[0][2],  Ush[0][3]);
    gate32<2> (A, Ush[1][0],  Ush[1][1],  Ush[1][2],  Ush[1][3]);
    gate32<4> (A, Ush[2][0],  Ush[2][1],  Ush[2][2],  Ush[2][3]);
    gate32<8> (A, Ush[3][0],  Ush[3][1],  Ush[3][2],  Ush[3][3]);
    gate32<16>(A, Ush[4][0],  Ush[4][1],  Ush[4][2],  Ush[4][3]);

    // Transpose 1: arr1 {0,9,10,11,12} -> arr2 {1,2,3,4,12}
    #pragma unroll
    for (int h = 0; h < 2; ++h) {
        __syncthreads();
        #pragma unroll
        for (int c = 0; c < 8; ++c) {
            int slot = ((t << 1) | (c << 9)) ^ (((t >> 4) & 7) << 1);
            f2 a0 = A[h*16 + 2*c], a1 = A[h*16 + 2*c + 1];
            *(float4*)&S[slot] = make_float4(a0.x, a0.y, a1.x, a1.y);
        }
        __syncthreads();
        #pragma unroll
        for (int rr = 0; rr < 16; ++rr) {
            int jj = (t & 1) | (rr << 1) | (((t >> 1) & 15) << 5) | (((t >> 5) & 7) << 9);
            A[h*16 + rr] = S[jj ^ (((t >> 1) & 7) << 1)];
        }
    }

    // arr2 gates: d1..4 -> q11,q10,q9,q8
    gate32<1>(A, Ush[5][0], Ush[5][1], Ush[5][2], Ush[5][3]);
    gate32<2>(A, Ush[6][0], Ush[6][1], Ush[6][2], Ush[6][3]);
    gate32<4>(A, Ush[7][0], Ush[7][1], Ush[7][2], Ush[7][3]);
    gate32<8>(A, Ush[8][0], Ush[8][1], Ush[8][2], Ush[8][3]);

    // Transpose 2: arr2 -> arr3 {5,6,7,8,12}
    #pragma unroll
    for (int h = 0; h < 2; ++h) {
        __syncthreads();
        #pragma unroll
        for (int rr = 0; rr < 16; ++rr) {
            int jj = (t & 1) | (rr << 1) | (((t >> 1) & 15) << 5) | (((t >> 5) & 7) << 9);
            S[jj ^ (((t >> 1) & 7) << 1)] = A[h*16 + rr];
        }
        __syncthreads();
        #pragma unroll
        for (int rr = 0; rr < 16; ++rr) {
            int jj = (t & 31) | (rr << 5) | (((t >> 5) & 7) << 9);
            A[h*16 + rr] = S[jj ^ ((rr & 7) << 1)];
        }
    }

    // arr3 gates: d5..8 -> q7,q6,q5,q4
    gate32<1>(A, Ush[9][0],  Ush[9][1],  Ush[9][2],  Ush[9][3]);
    gate32<2>(A, Ush[10][0], Ush[10][1], Ush[10][2], Ush[10][3]);
    gate32<4>(A, Ush[11][0], Ush[11][1], Ush[11][2], Ush[11][3]);
    gate32<8>(A, Ush[12][0], Ush[12][1], Ush[12][2], Ush[12][3]);

    // direct store from arr3 (no perm)
    #pragma unroll
    for (int h = 0; h < 2; ++h) {
        #pragma unroll
        for (int rr = 0; rr < 16; ++rr) {
            int d = (t & 31) | (rr << 5) | (((t >> 5) & 7) << 9) | (h << 12);
            int m = (d & 511) | (fixb << 9) | (((d >> 9) & 1) << 12) | ((d >> 10) << 13);
            base[m] = A[h*16 + rr];
        }
    }
}

// Sweep 1: fused analytic generation + L1 x13.  No amplitude loads at all.
// Register slot a at thread t, block (b,fixb) holds dest index g:
//   g0..2 = a2,a3,a4; g3 = a0; g4..11 = t0..7; g12..14 = fixb; g15 = a1.
// Source s = F^{-1}(g):  s0=a2^a3, s1=a3^a4, s2=a4^a0, s3=a0^t0,
//   s4..s10 = t_{b-4}^t_{b-3}, s11=t7^fixb0, s12=fixb0^fixb1, s13=fixb1^fixb2,
//   s14=fixb2^a1^a2, s15=a1^a2.  amp = prod_beta V[beta][s_beta].
// Product tree over (a0, e1=a1^a2, e2=a2^a3, e3=a3^a4, e4=a4^a0): 61 cmul.
__global__ __launch_bounds__(TPB, 4) void qc_B1_gen(
    const float* __restrict__ x, const float* __restrict__ params,
    f2* __restrict__ st)
{
    __shared__ __align__(16) f2 S[4096];       // 32 KB transpose buffer
    __shared__ f2 Ush[13][4];
    __shared__ f2 V[16][2];

    const int t    = threadIdx.x;
    const int b    = blockIdx.x >> 3;
    const int fixb = blockIdx.x & 7;            // g bits 12..14
    f2* base = st + ((size_t)b << NQ);

    if (t < 16) {                               // qubit t, g bit 15-t
        f2 U[4];
        computeU(params, 0, t, U);
        float s, c;
        sincosf(0.5f * x[b*NQ + t], &s, &c);
        // w = U * (cos h, -i sin h)^T
        V[15 - t][0] = (f2){U[0].x*c + U[1].y*s, U[0].y*c - U[1].x*s};
        V[15 - t][1] = (f2){U[2].x*c + U[3].y*s, U[2].y*c - U[3].x*s};
    } else if (t < 29) {                        // layer-1 gate table
        int tt = t - 16;
        int qb = (tt == 0) ? 12 : (tt == 1) ? 0 : (tt < 5) ? (17 - tt) : (16 - tt);
        computeU(params, 1, qb, Ush[tt]);
    }
    __syncthreads();                             // V + Ush ready

    const int f0 = fixb & 1, f1 = (fixb >> 1) & 1, f2b = (fixb >> 2) & 1;
    const int t0 = t & 1,  t7 = (t >> 7) & 1;

    // pre = prod_{beta=4..13}
    f2 pre = V[4][(t ^ (t >> 1)) & 1];
    #pragma unroll
    for (int bb = 5; bb <= 10; ++bb)
        pre = cmulpk(pre, V[bb][((t >> (bb - 4)) ^ (t >> (bb - 3))) & 1]);
    pre = cmulpk(pre, V[11][t7 ^ f0]);
    pre = cmulpk(pre, V[12][f0 ^ f1]);
    pre = cmulpk(pre, V[13][f1 ^ f2b]);

    f2 P0 = cmulpk(pre, V[3][t0]);               // a0=0
    f2 P1 = cmulpk(pre, V[3][1 ^ t0]);           // a0=1
    f2 Q[4];                                     // Q[a0 + 2*e4] = P[a0]*V[2][e4]
    Q[0] = cmulpk(P0, V[2][0]); Q[1] = cmulpk(P1, V[2][0]);
    Q[2] = cmulpk(P0, V[2][1]); Q[3] = cmulpk(P1, V[2][1]);
    f2 Rr[4];                                    // Rr[e2 + 2*e3] = V[0][e2]*V[1][e3]
    Rr[0] = cmulpk(V[0][0], V[1][0]); Rr[1] = cmulpk(V[0][1], V[1][0]);
    Rr[2] = cmulpk(V[0][0], V[1][1]); Rr[3] = cmulpk(V[0][1], V[1][1]);
    f2 G0 = cmulpk(V[15][0], V[14][f2b]);        // e1=0
    f2 G1 = cmulpk(V[15][1], V[14][1 ^ f2b]);    // e1=1
    f2 TT[8];                                    // TT[e1 + 2*e2 + 4*e3]
    #pragma unroll
    for (int e = 0; e < 4; ++e) {
        TT[2*e]     = cmulpk(G0, Rr[e]);
        TT[2*e + 1] = cmulpk(G1, Rr[e]);
    }

    f2 A[32];
    #pragma unroll
    for (int a = 0; a < 32; ++a) {
        const int a0 = a & 1;
        const int e1 = ((a >> 1) ^ (a >> 2)) & 1;
        const int e2 = ((a >> 2) ^ (a >> 3)) & 1;
        const int e3 = ((a >> 3) ^ (a >> 4)) & 1;
        const int e4 = ((a >> 4) ^  a      ) & 1;
        A[a] = cmulpk(Q[a0 + 2*e4], TT[e1 + 2*e2 + 4*e3]);
    }

    b_gates_and_store(A, S, Ush, t, fixb, base);
}

// Sweeps 3,5: tail(lm-1) rename + layer-lm gates on all 13 B-local qubits.
__global__ __launch_bounds__(TPB, 4) void qc_B_heavy(
    const float* __restrict__ params, f2* __restrict__ st, int lm)
{
    __shared__ __align__(16) f2 S[4096];       // 32 KB, one d12 half at a time
    __shared__ f2 Ush[13][4];

    const int t    = threadIdx.x;
    const int b    = blockIdx.x >> 3;
    const int fixb = blockIdx.x & 7;            // g bits 12..14
    f2* base = st + ((size_t)b << NQ);

    // Ush slots: 0:q12(d0) 1:q0(d9) 2:q15(d10) 3:q14(d11) 4:q13(d12)
    //            5..8: q11..q8 (d1..4)   9..12: q7..q4 (d5..8)
    if (t < 13) {
        int qb = (t == 0) ? 12 : (t == 1) ? 0 : (t < 5) ? (17 - t) : (16 - t);
        computeU(params, lm, qb, Ush[t]);
    }

    // load arr1-d: reg a: bit0 = d0, bits1..4 = d9..12; thread bits = d1..8
    f2 R[32];
    #pragma unroll
    for (int k = 0; k < 16; ++k) {
        int j = 2*(t + 256*k);
        int m = (j & 511) | (fixb << 9) | (((j >> 9) & 1) << 12) | ((j >> 10) << 13);
        float4 v = *(const float4*)(base + m);
        R[2*k]   = (f2){v.x, v.y};
        R[2*k+1] = (f2){v.z, v.w};
    }
    // tail perm of layer lm-1: pure compile-time register rename
    f2 A[32];
    #pragma unroll
    for (int a = 0; a < 32; ++a) A[a] = R[permB(a)];
    __syncthreads();                             // Ush ready

    b_gates_and_store(A, S, Ush, t, fixb, base);
}

// Sweeps 2,4: layer-l gates q3,q2,q1 (j9,j10,j11) + main(l) perm in writeback.
__global__ __launch_bounds__(TPB, 4) void qc_A_lite(
    const float* __restrict__ params, f2* __restrict__ st, int layer)
{
    __shared__ __align__(16) f2 S[4096];
    __shared__ f2 Ush[3][4];
    const int t    = threadIdx.x;
    const int b    = blockIdx.x >> 3;
    const int fix3 = blockIdx.x & 7;
    f2* base = st + ((size_t)b << NQ) + (fix3 << 13);

    if (t < 3) computeU(params, layer, 3 - t, Ush[t]);   // Ush[0]=q3 Ush[1]=q2 Ush[2]=q1

    f2 A[32];
    const float4* src = (const float4*)base;
    #pragma unroll
    for (int k = 0; k < 16; ++k) {
        float4 v = src[t + 256*k];
        A[2*k]   = (f2){v.x, v.y};
        A[2*k+1] = (f2){v.z, v.w};
    }
    __syncthreads();                             // Ush ready

    gate32<2>(A, Ush[0][0], Ush[0][1], Ush[0][2], Ush[0][3]);   // j9  q3
    gate32<4>(A, Ush[1][0], Ush[1][1], Ush[1][2], Ush[1][3]);   // j10 q2
    gate32<8>(A, Ush[2][0], Ush[2][1], Ush[2][2], Ush[2][3]);   // j11 q1

    // writeback: stage at arr1 positions, read with main-chain perm, store coalesced
    float4* dst = (float4*)base;
    #pragma unroll
    for (int h = 0; h < 2; ++h) {
        __syncthreads();
        #pragma unroll
        for (int c = 0; c < 8; ++c) {            // arr1: j = o | (t<<1) | (c<<9), j12=h
            int slot = ((t << 1) | (c << 9)) ^ (((t >> 4) & 7) << 1);
            f2 a0 = A[h*16 + 2*c], a1 = A[h*16 + 2*c + 1];
            *(float4*)&S[slot] = make_float4(a0.x, a0.y, a1.x, a1.y);
        }
        __syncthreads();
        #pragma unroll
        for (int k = 0; k < 8; ++k) {            // dest d' = 2(t+256k), bit12 = h
            int d  = 2*(t + 256*k);
            int i0 = d ^ (d >> 1) ^ (h << 11);
            int i1 = (d+1) ^ ((d+1) >> 1) ^ (h << 11);
            f2 a0 = S[i0 ^ (((i0 >> 5) & 7) << 1)];
            f2 a1 = S[i1 ^ (((i1 >> 5) & 7) << 1)];
            dst[(t + 256*k) | (h << 11)] = make_float4(a0.x, a0.y, a1.x, a1.y);
        }
    }
}

// Sweep 6: L3 gates q3,q2,q1, then expZ with main3.tail3 folded as relabel.
// u bits: 0..2 = fix3, 3 = a0, 4..11 = t, 12..15 = a1..a4.
// f_b = parity(u>>b) (b<=14), f15 = parity(u & 0x7FFF).
__global__ __launch_bounds__(TPB) void qc_A_final(
    const float* __restrict__ params, const f2* __restrict__ st,
    float* __restrict__ out)
{
    __shared__ f2 Ush[3][4];
    const int t    = threadIdx.x;
    const int b    = blockIdx.x >> 3;
    const int fix3 = blockIdx.x & 7;
    const f2* base = st + ((size_t)b << NQ) + (fix3 << 13);

    if (t < 3) computeU(params, 3, 3 - t, Ush[t]);

    f2 A[32];
    const float4* src = (const float4*)base;
    #pragma unroll
    for (int k = 0; k < 16; ++k) {
        float4 v = src[t + 256*k];
        A[2*k]   = (f2){v.x, v.y};
        A[2*k+1] = (f2){v.z, v.w};
    }
    __syncthreads();

    gate32<2>(A, Ush[0][0], Ush[0][1], Ush[0][2], Ush[0][3]);   // j9  q3
    gate32<4>(A, Ush[1][0], Ush[1][1], Ush[1][2], Ush[1][3]);   // j10 q2
    gate32<8>(A, Ush[2][0], Ush[2][1], Ush[2][2], Ush[2][3]);   // j11 q1

    // 5 register-parity sign buckets:
    // M1 = par(a1..a4) -> q3..q11 ; M2 = par(a0..a4) -> q12..q15
    // M3 = par(a2..a4) -> q2 ; M4 = par(a3,a4) -> q1 ; M5 = par(a0..a3) -> q0
    float m1 = 0.f, m2 = 0.f, m3 = 0.f, m4 = 0.f, m5 = 0.f;
    #pragma unroll
    for (int a = 0; a < 32; ++a) {
        float p = A[a].x*A[a].x + A[a].y*A[a].y;
        m1 += (__popc(a & 0x1E) & 1) ? -p : p;
        m2 += (__popc(a & 0x1F) & 1) ? -p : p;
        m3 += (__popc(a & 0x1C) & 1) ? -p : p;
        m4 += (__popc(a & 0x18) & 1) ? -p : p;
        m5 += (__popc(a & 0x0F) & 1) ? -p : p;
    }
    const int pt = __popc(t) & 1;
    const int pf = __popc(fix3) & 1;
    float acc[NQ];
    acc[0] = ((pt ^ pf) & 1) ? -m5 : m5;         // f15
    acc[1] = m4;                                  // f14
    acc[2] = m3;                                  // f13
    acc[3] = m1;                                  // f12
    #pragma unroll
    for (int q = 4; q <= 11; ++q) {               // f_{15-q}: t-part = par(t >> (11-q))
        int s = __popc(t >> (11 - q)) & 1;
        acc[q] = s ? -m1 : m1;
    }
    acc[12] = pt ? -m2 : m2;
    acc[13] = ((pt ^ (fix3 >> 2)) & 1) ? -m2 : m2;
    acc[14] = ((pt ^ __popc(fix3 >> 1)) & 1) ? -m2 : m2;
    acc[15] = ((pt ^ pf) & 1) ? -m2 : m2;

    #pragma unroll
    for (int q = 0; q < NQ; ++q) {
        float v = acc[q];
        v += __shfl_down(v, 32, 64);
        v += __shfl_down(v, 16, 64);
        v += __shfl_down(v,  8, 64);
        v += __shfl_down(v,  4, 64);
        v += __shfl_down(v,  2, 64);
        v += __shfl_down(v,  1, 64);
        acc[q] = v;
    }
    if ((t & 63) == 0) {
        #pragma unroll
        for (int q = 0; q < NQ; ++q)
            atomicAdd(&out[b*NQ + q], acc[q]);
    }
}

extern "C" void kernel_launch(void* const* d_in, const int* in_sizes, int n_in,
                              void* d_out, int out_size, void* d_ws, size_t ws_size,
                              hipStream_t stream)
{
    (void)in_sizes; (void)n_in; (void)ws_size;
    const float* x      = (const float*)d_in[0];   // (512,16) fp32
    const float* params = (const float*)d_in[1];   // (4,16,3) fp32
    float* out = (float*)d_out;                    // (512,16) fp32
    f2* st = (f2*)d_ws;                            // 256 MiB state

    hipMemsetAsync(d_out, 0, (size_t)out_size * sizeof(float), stream);
    qc_B1_gen <<<dim3(512*8), dim3(TPB), 0, stream>>>(x, params, st);
    qc_A_lite <<<dim3(512*8), dim3(TPB), 0, stream>>>(params, st, 1);
    qc_B_heavy<<<dim3(512*8), dim3(TPB), 0, stream>>>(params, st, 2);
    qc_A_lite <<<dim3(512*8), dim3(TPB), 0, stream>>>(params, st, 2);
    qc_B_heavy<<<dim3(512*8), dim3(TPB), 0, stream>>>(params, st, 3);
    qc_A_final<<<dim3(512*8), dim3(TPB), 0, stream>>>(params, st, out);
}